// Round 5
// baseline (373.702 us; speedup 1.0000x reference)
//
#include <hip/hip_runtime.h>
#include <math.h>

#define NV 10000
#define B 512
#define L 256
#define E 64

typedef _Float16 f16;
typedef _Float16 f16x8 __attribute__((ext_vector_type(8)));
typedef float f32x4 __attribute__((ext_vector_type(4)));
typedef int v8i __attribute__((ext_vector_type(8)));

// ws layout (f32 offsets)
#define OFF_WA1HT 0u         // [256][256] f32  Wa1hT[k*256+j] = Wa1[j*512+k]
#define OFF_WC1T  65536u     // [256][256] f32
#define OFF_WB    131072u    // 262144 B: fp8 frags of 8*W_hh for mfma_scale 16x16x128
#define OFF_WIHF  196608u    // 262144 f16: frags of W_ih (16x16x32 f16 layout)
#define OFF_WA1NF 327680u    // 65536 f16: frags of Wa1n
#define OFF_PEMB  360448u    // 10,240,000 f32: P_perm[v][hc*4+q] = 128*(ge@W_ih^T+b)[v][q*256+hc]
#define OFF_AEMB  10600448u  // 2,560,000 f16: A_emb[v][256]
// total 11,880,448 f32 = 47.5 MB

__device__ __forceinline__ int fp8_byte(float x) {
  return __builtin_amdgcn_cvt_pk_fp8_f32(x, x, 0, false) & 0xFF;
}
__device__ __forceinline__ unsigned int fp8_pk(float x, float y) {
  return (unsigned int)__builtin_amdgcn_cvt_pk_fp8_f32(x, y, 0, false);
}

#define MFMA_SC(a, b, c) \
  __builtin_amdgcn_mfma_scale_f32_16x16x128_f8f6f4((a), (b), (c), 0, 0, 0, 127, 0, 127)

// k-permutation applied to both hA bytes and W_hh frag k-index:
// byte position b within a 256-k row holds original k = PI(b) = (b&1)*128 + b/2.
// Contraction is invariant since A and B use the same permutation. This makes
// h[hc] and h[hc+128] (one lane's two columns) adjacent bytes -> b16 writes.
__device__ __forceinline__ int PI(int b) { return ((b & 1) << 7) | (b >> 1); }

__global__ __launch_bounds__(256) void k_prep(
    const float* __restrict__ W_ih, const float* __restrict__ W_hh,
    const float* __restrict__ Wa1, const float* __restrict__ Wc1,
    float* __restrict__ ws) {
  int idx = blockIdx.x * 256 + threadIdx.x;
  if (idx < 65536) {  // W_hh fp8 frags (x8) for 16x16x128: dword idx
    int d = idx & 7, lane = (idx >> 3) & 63, kt = (idx >> 9) & 1;
    int q = (idx >> 10) & 3, w = (idx >> 12) & 15;
    int l15 = lane & 15, quad = lane >> 4;
    int n = q * 256 + w * 16 + l15;
    int kb = kt * 128 + quad * 32 + d * 4;
    unsigned int word = 0;
#pragma unroll
    for (int jb = 0; jb < 4; ++jb)
      word |= ((unsigned int)fp8_byte(W_hh[n * 256 + PI(kb + jb)] * 8.f)) << (8 * jb);
    ((unsigned int*)(ws + OFF_WB))[idx] = word;
    return;
  }
  int p1 = idx - 65536;
  if (p1 < 262144) {  // W_ih f16 frags (16x16x32 layout, for k_pemb)
    int j = p1 & 7, lane = (p1 >> 3) & 63, kt = (p1 >> 9) & 7;
    int q = (p1 >> 12) & 3, w = (p1 >> 14) & 15;
    int n = q * 256 + w * 16 + (lane & 15);
    int k = kt * 32 + (lane >> 4) * 8 + j;
    ((f16*)(ws + OFF_WIHF))[p1] = (f16)W_ih[n * 256 + k];
    return;
  }
  int p2 = p1 - 262144;
  if (p2 < 65536) {  // Wa1n f16 frags
    int j = p2 & 7, lane = (p2 >> 3) & 63, kt = (p2 >> 9) & 7, w = (p2 >> 12) & 15;
    int n = w * 16 + (lane & 15);
    int k = kt * 32 + (lane >> 4) * 8 + j;
    ((f16*)(ws + OFF_WA1NF))[p2] = (f16)Wa1[n * 512 + 256 + k];
    return;
  }
  int i2 = p2 - 65536;
  if (i2 < 65536) {  // actor/critic transposes
    int k = i2 >> 8, j = i2 & 255;
    ws[OFF_WA1HT + i2] = Wa1[j * 512 + k];
    ws[OFF_WC1T + i2] = Wc1[j * 256 + k];
  }
}

// Fused P_emb + A_emb via f16 MFMA. 32 vertices/block, 1024 threads.
__global__ __launch_bounds__(1024) void k_pemb(
    const float* __restrict__ ge, const float* __restrict__ b_ih,
    const float* __restrict__ b_hh, float* __restrict__ ws) {
  __shared__ f16 Alds[32 * 264];
  const int tid = threadIdx.x, w = tid >> 6, lane = tid & 63;
  const int l15 = lane & 15, quad = lane >> 4;
  const int vbase = blockIdx.x * 32;
  for (int i = tid; i < 32 * 256; i += 1024) {
    int row = i >> 8, col = i & 255;
    int v = min(vbase + row, NV - 1);
    Alds[row * 264 + col] = (f16)ge[(size_t)v * 256 + col];
  }
  __syncthreads();
  const f16* __restrict__ WIHF = (const f16*)(ws + OFF_WIHF);
  const f16* __restrict__ WANF = (const f16*)(ws + OFF_WA1NF);
  f32x4 Cp[2][4], Ca[2];
#pragma unroll
  for (int t = 0; t < 2; ++t) {
    Ca[t] = (f32x4){0.f, 0.f, 0.f, 0.f};
#pragma unroll
    for (int q = 0; q < 4; ++q) Cp[t][q] = (f32x4){0.f, 0.f, 0.f, 0.f};
  }
#pragma unroll
  for (int kt = 0; kt < 8; ++kt) {
    f16x8 a0 = *(const f16x8*)(Alds + l15 * 264 + kt * 32 + quad * 8);
    f16x8 a1 = *(const f16x8*)(Alds + (l15 + 16) * 264 + kt * 32 + quad * 8);
#pragma unroll
    for (int q = 0; q < 4; ++q) {
      f16x8 bq = *(const f16x8*)(WIHF + (size_t)(((w * 4 + q) * 8 + kt) * 512 + lane * 8));
      Cp[0][q] = __builtin_amdgcn_mfma_f32_16x16x32_f16(a0, bq, Cp[0][q], 0, 0, 0);
      Cp[1][q] = __builtin_amdgcn_mfma_f32_16x16x32_f16(a1, bq, Cp[1][q], 0, 0, 0);
    }
    f16x8 bn = *(const f16x8*)(WANF + (size_t)((w * 8 + kt) * 512 + lane * 8));
    Ca[0] = __builtin_amdgcn_mfma_f32_16x16x32_f16(a0, bn, Ca[0], 0, 0, 0);
    Ca[1] = __builtin_amdgcn_mfma_f32_16x16x32_f16(a1, bn, Ca[1], 0, 0, 0);
  }
  const int hc = w * 16 + l15;
  float bias[4];
#pragma unroll
  for (int q = 0; q < 4; ++q) {
    int n = q * 256 + hc;
    bias[q] = b_ih[n] + b_hh[n];
  }
  float* __restrict__ P = ws + OFF_PEMB;
  f16* __restrict__ A = (f16*)(ws + OFF_AEMB);
#pragma unroll
  for (int tile = 0; tile < 2; ++tile)
#pragma unroll
    for (int reg = 0; reg < 4; ++reg) {
      int v = vbase + tile * 16 + quad * 4 + reg;
      if (v < NV) {
        f32x4 pw;
#pragma unroll
        for (int q = 0; q < 4; ++q) pw[q] = 128.f * (Cp[tile][q][reg] + bias[q]);
        *(f32x4*)(P + (size_t)v * 1024 + hc * 4) = pw;
        A[(size_t)v * 256 + hc] = (f16)Ca[tile][reg];
      }
    }
}

// LSTM + fused heads: 256 blocks x 512 threads (8 waves), 2 paths/block.
// Each wave owns 8 N-tiles (Bf[8][2] = 128 persistent VGPR, 16 MFMA/step) and
// each lane two gate columns hc, hc+128. hA: 4 phys rows {p0hi,p0lo,p1hi,p1lo},
// k-bytes PI-permuted so (hc, hc+128) are adjacent -> 2 ds_write_b16 per writer.
// Per-CU LDS ops per step halve vs 16-wave version (matrix floor unchanged).
__global__ __launch_bounds__(512, 2) void k_lstm(
    const int* __restrict__ paths, const int* __restrict__ path_lens,
    const int* __restrict__ neighbors, const int* __restrict__ n_nb,
    const float* __restrict__ ba1, const float* __restrict__ Wa2,
    const float* __restrict__ ba2, const float* __restrict__ bc1,
    const float* __restrict__ Wc2, const float* __restrict__ bc2,
    float* __restrict__ out, float* __restrict__ ws) {
  const int tid = threadIdx.x, w = tid >> 6, lane = tid & 63;  // w in 0..7
  const int l15 = lane & 15, quad = lane >> 4;
  const int g2 = blockIdx.x * 2;

  __shared__ char hA[2][4 * 272];    // [parity][phys*272 + b], b PI-permuted
  __shared__ int vtx[2][256];        // staged path vertex ids
  __shared__ float hfin[2][257];
  __shared__ float u_s[2][264];      // padded: index j + (j>>5)
  __shared__ float vredS[2][256];
  __shared__ float part4[2][64][5];

  for (int i = tid; i < 2 * 4 * 272 / 4; i += 512) ((int*)hA)[i] = 0;
  vtx[tid >> 8][tid & 255] = paths[(g2 + (tid >> 8)) * L + (tid & 255)];

  const int len0 = path_lens[g2], len1 = path_lens[g2 + 1];
  const int lmax = max(len0, len1);

  // persistent B-frags: wave w owns n-tile groups wp=w and wp=w+8 (128 VGPR)
  const v8i* __restrict__ WBv = (const v8i*)(ws + OFF_WB);
  v8i Bf[8][2];
#pragma unroll
  for (int qq = 0; qq < 8; ++qq) {
    const int wp = (qq < 4) ? w : (w + 8);
    const int q = qq & 3;
#pragma unroll
    for (int kt = 0; kt < 2; ++kt)
      Bf[qq][kt] = WBv[(size_t)(((wp * 4 + q) * 2 + kt) * 64 + lane)];
  }

  const char* __restrict__ Pb = (const char*)(ws + OFF_PEMB);
  const int hc = w * 16 + l15;           // first column; second is hc+128
  const int path = quad >> 1;            // 0,0,1,1 per quad
  const int lenv = path ? len1 : len0;
  const unsigned loff = (unsigned)hc * 16u;
  const int physr = ((l15 >> 3) << 1) | (l15 & 1);  // A-read phys row

  float cst0 = 0.f, hst0 = 0.f, cst1 = 0.f, hst1 = 0.f;
  f32x4 Cf[8];
#pragma unroll
  for (int qq = 0; qq < 8; ++qq) Cf[qq] = (f32x4){0.f, 0.f, 0.f, 0.f};
  __syncthreads();

  // P prefetch: pva/pvb = P rows (cols hc / hc+128) for step t; vn = vertex t+1
  f32x4 pva = *(const f32x4*)(Pb + (unsigned)vtx[path][0] * 4096u + loff);
  f32x4 pvb = *(const f32x4*)(Pb + (unsigned)vtx[path][0] * 4096u + loff + 2048u);
  int vn = vtx[path][1];

  for (int t = 0; t < lmax; ++t) {
    // a-frags first (broadcast reads)
    const char* hp = hA[t & 1];
    const v8i a0 = *(const v8i*)(hp + physr * 272 + quad * 32);
    const v8i a1 = *(const v8i*)(hp + physr * 272 + 128 + quad * 32);
    const int vn2 = vtx[path][min(t + 2, L - 1)];

    // C init: reg0 carries P, reg1 zero; regs [2],[3] hold harmless dupes
#pragma unroll
    for (int q = 0; q < 4; ++q) {
      Cf[q][0] = pva[q];     Cf[q][1] = 0.f;
      Cf[q + 4][0] = pvb[q]; Cf[q + 4][1] = 0.f;
    }

    // next-step P prefetch (stays in flight across the raw barrier)
    const f32x4 pvna = *(const f32x4*)(Pb + (unsigned)vn * 4096u + loff);
    const f32x4 pvnb = *(const f32x4*)(Pb + (unsigned)vn * 4096u + loff + 2048u);

    __builtin_amdgcn_s_setprio(1);
#pragma unroll
    for (int qq = 0; qq < 8; ++qq) Cf[qq] = MFMA_SC(a0, Bf[qq][0], Cf[qq]);
#pragma unroll
    for (int qq = 0; qq < 8; ++qq) Cf[qq] = MFMA_SC(a1, Bf[qq][1], Cf[qq]);
    __builtin_amdgcn_s_setprio(0);

    // in-lane hi+lo combine, two columns
    float G0[4], G1[4];
#pragma unroll
    for (int q = 0; q < 4; ++q) {
      G0[q] = Cf[q][0] + Cf[q][1];
      G1[q] = Cf[q + 4][0] + Cf[q + 4][1];
    }

    const float inv = 1.f / 128.f;
    {
      const float si = __builtin_amdgcn_rcpf(1.f + __expf(-G0[0] * inv));
      const float sf = __builtin_amdgcn_rcpf(1.f + __expf(-G0[1] * inv));
      const float tg = 1.f - 2.f * __builtin_amdgcn_rcpf(__expf(2.f * G0[2] * inv) + 1.f);
      const float so = __builtin_amdgcn_rcpf(1.f + __expf(-G0[3] * inv));
      const float cn = sf * cst0 + si * tg;
      const float hn = so * (1.f - 2.f * __builtin_amdgcn_rcpf(__expf(2.f * cn) + 1.f));
      if (t < lenv) { cst0 = cn; hst0 = hn; }
    }
    {
      const float si = __builtin_amdgcn_rcpf(1.f + __expf(-G1[0] * inv));
      const float sf = __builtin_amdgcn_rcpf(1.f + __expf(-G1[1] * inv));
      const float tg = 1.f - 2.f * __builtin_amdgcn_rcpf(__expf(2.f * G1[2] * inv) + 1.f);
      const float so = __builtin_amdgcn_rcpf(1.f + __expf(-G1[3] * inv));
      const float cn = sf * cst1 + si * tg;
      const float hn = so * (1.f - 2.f * __builtin_amdgcn_rcpf(__expf(2.f * cn) + 1.f));
      if (t < lenv) { cst1 = cn; hst1 = hn; }
    }

    if (!(quad & 1)) {  // quad0 writes path0 rows (phys 0,1); quad2 -> path1 (2,3)
      char* nh = hA[(t + 1) & 1];
      const unsigned int hp2 = fp8_pk(16.f * hst0, 16.f * hst1);
      const float d0 = __builtin_amdgcn_cvt_f32_fp8((int)hp2, 0);
      const float d1 = __builtin_amdgcn_cvt_f32_fp8((int)hp2, 1);
      const unsigned int lp2 = fp8_pk(16.f * hst0 - d0, 16.f * hst1 - d1);
      // byte 2*hc = col hc (even b: PI=b/2), byte 2*hc+1 = col hc+128
      *(short*)(nh + (path * 2 + 0) * 272 + 2 * hc) = (short)(hp2 & 0xFFFF);
      *(short*)(nh + (path * 2 + 1) * 272 + 2 * hc) = (short)(lp2 & 0xFFFF);
    }
    pva = pvna;
    pvb = pvnb;
    vn = vn2;
    // raw barrier: fence LDS only, leave the global P prefetch in flight
    __builtin_amdgcn_sched_barrier(0);
    asm volatile("s_waitcnt lgkmcnt(0)" ::: "memory");
    __builtin_amdgcn_s_barrier();
    __builtin_amdgcn_sched_barrier(0);
  }

  // ---- fused heads for this block's 2 paths ----
  if (!(quad & 1)) {
    hfin[path][hc] = hst0;
    hfin[path][hc + 128] = hst1;
  }
  __syncthreads();

  const float* __restrict__ Wa1hT = ws + OFF_WA1HT;
  const float* __restrict__ Wc1T = ws + OFF_WC1T;
  const int p = tid >> 8;          // 0..1
  const int jj = tid & 255;
  float aa = ba1[jj], cc = bc1[jj];
  for (int k = 0; k < 256; ++k) {
    const float hk = hfin[p][k];
    aa += Wa1hT[k * 256 + jj] * hk;
    cc += Wc1T[k * 256 + jj] * hk;
  }
  u_s[p][jj + (jj >> 5)] = aa;
  cc = cc > 0.f ? cc : __expf(cc) - 1.f;
  vredS[p][jj] = cc * Wc2[jj];
  __syncthreads();
  if (tid < 128) {
    const int pp = tid >> 6, lp = tid & 63;
    float s = vredS[pp][lp] + vredS[pp][lp + 64] + vredS[pp][lp + 128] + vredS[pp][lp + 192];
#pragma unroll
    for (int d = 32; d > 0; d >>= 1) s += __shfl_xor(s, d, 64);
    if (lp == 0) out[B * E + g2 + pp] = s + bc2[0];
  }
  // actor logits: (pa, e, jh) -> 64-long j-chunk
  const f16* __restrict__ A = (const f16*)(ws + OFF_AEMB);
  const int pa = tid >> 8, e = (tid >> 2) & 63, jh = tid & 3;
  const int nbv = neighbors[(g2 + pa) * 64 + e];
  float s = 0.f;
  const f16x8* __restrict__ Arow = (const f16x8*)(A + (size_t)nbv * 256 + jh * 64);
#pragma unroll
  for (int jo = 0; jo < 8; ++jo) {
    const f16x8 av = Arow[jo];
#pragma unroll
    for (int u = 0; u < 8; ++u) {
      const int j = jh * 64 + jo * 8 + u;
      float a = u_s[pa][j + (j >> 5)] + (float)av[u];
      a = a > 0.f ? a : __expf(a) - 1.f;
      s += a * Wa2[j];
    }
  }
  part4[pa][e][jh] = s;
  __syncthreads();
  if (tid < 128) {
    const int pp = tid >> 6, ee = tid & 63;
    const int ne = n_nb[g2 + pp];
    const bool valid = ee < ne;
    float le = -1e30f;
    if (valid) {
      le = ba2[0] + part4[pp][ee][0] + part4[pp][ee][1] + part4[pp][ee][2] + part4[pp][ee][3];
    }
    float m = le;
#pragma unroll
    for (int d = 32; d > 0; d >>= 1) m = fmaxf(m, __shfl_xor(m, d, 64));
    float pe = valid ? __expf(le - m) : 0.f;
    float sm = pe;
#pragma unroll
    for (int d = 32; d > 0; d >>= 1) sm += __shfl_xor(sm, d, 64);
    out[(g2 + pp) * 64 + ee] = pe / sm;
  }
}

extern "C" void kernel_launch(void* const* d_in, const int* in_sizes, int n_in,
                              void* d_out, int out_size, void* d_ws, size_t ws_size,
                              hipStream_t stream) {
  (void)in_sizes; (void)n_in; (void)out_size; (void)ws_size;
  const float* graph_emb = (const float*)d_in[0];
  const int* paths       = (const int*)d_in[1];
  const int* path_lens   = (const int*)d_in[2];
  const int* neighbors   = (const int*)d_in[3];
  const int* n_nb        = (const int*)d_in[4];
  const float* W_ih = (const float*)d_in[5];
  const float* W_hh = (const float*)d_in[6];
  const float* b_ih = (const float*)d_in[7];
  const float* b_hh = (const float*)d_in[8];
  const float* Wa1  = (const float*)d_in[9];
  const float* ba1  = (const float*)d_in[10];
  const float* Wa2  = (const float*)d_in[11];
  const float* ba2  = (const float*)d_in[12];
  const float* Wc1  = (const float*)d_in[13];
  const float* bc1  = (const float*)d_in[14];
  const float* Wc2  = (const float*)d_in[15];
  const float* bc2  = (const float*)d_in[16];
  float* out = (float*)d_out;
  float* ws = (float*)d_ws;

  hipLaunchKernelGGL(k_prep, dim3(1792), dim3(256), 0, stream, W_ih, W_hh, Wa1, Wc1, ws);
  hipLaunchKernelGGL(k_pemb, dim3(313), dim3(1024), 0, stream, graph_emb, b_ih, b_hh, ws);
  hipLaunchKernelGGL(k_lstm, dim3(256), dim3(512), 0, stream, paths, path_lens,
                     neighbors, n_nb, ba1, Wa2, ba2, bc1, Wc2, bc2, out, ws);
}

// Round 6
// 366.106 us; speedup vs baseline: 1.0207x; 1.0207x over previous
//
#include <hip/hip_runtime.h>
#include <math.h>

#define NV 10000
#define B 512
#define L 256
#define E 64

typedef _Float16 f16;
typedef _Float16 f16x8 __attribute__((ext_vector_type(8)));
typedef float f32x4 __attribute__((ext_vector_type(4)));
typedef int v8i __attribute__((ext_vector_type(8)));

// ws layout (f32 offsets)
#define OFF_WA1HT 0u         // [256][256] f32  Wa1hT[k*256+j] = Wa1[j*512+k]
#define OFF_WC1T  65536u     // [256][256] f32
#define OFF_WB    131072u    // 262144 B: fp8 frags of 8*W_hh for mfma_scale 16x16x128
#define OFF_WIHF  196608u    // 262144 f16: frags of W_ih (16x16x32 f16 layout)
#define OFF_WA1NF 327680u    // 65536 f16: frags of Wa1n
#define OFF_PEMB  360448u    // 10,240,000 f32: P_perm[v][hc*4+q] = 128*(ge@W_ih^T+b)[v][q*256+hc]
#define OFF_AEMB  10600448u  // 2,560,000 f16: A_emb[v][256]
// total 11,880,448 f32 = 47.5 MB

__device__ __forceinline__ int fp8_byte(float x) {
  return __builtin_amdgcn_cvt_pk_fp8_f32(x, x, 0, false) & 0xFF;
}

#define MFMA_SC(a, b, c) \
  __builtin_amdgcn_mfma_scale_f32_16x16x128_f8f6f4((a), (b), (c), 0, 0, 0, 127, 0, 127)

__global__ __launch_bounds__(256) void k_prep(
    const float* __restrict__ W_ih, const float* __restrict__ W_hh,
    const float* __restrict__ Wa1, const float* __restrict__ Wc1,
    float* __restrict__ ws) {
  int idx = blockIdx.x * 256 + threadIdx.x;
  if (idx < 65536) {  // W_hh fp8 frags (x8) for 16x16x128: dword idx
    int d = idx & 7, lane = (idx >> 3) & 63, kt = (idx >> 9) & 1;
    int q = (idx >> 10) & 3, w = (idx >> 12) & 15;
    int l15 = lane & 15, quad = lane >> 4;
    int n = q * 256 + w * 16 + l15;
    int kb = kt * 128 + quad * 32 + d * 4;
    unsigned int word = 0;
#pragma unroll
    for (int jb = 0; jb < 4; ++jb)
      word |= ((unsigned int)fp8_byte(W_hh[n * 256 + kb + jb] * 8.f)) << (8 * jb);
    ((unsigned int*)(ws + OFF_WB))[idx] = word;
    return;
  }
  int p1 = idx - 65536;
  if (p1 < 262144) {  // W_ih f16 frags (16x16x32 layout, for k_pemb)
    int j = p1 & 7, lane = (p1 >> 3) & 63, kt = (p1 >> 9) & 7;
    int q = (p1 >> 12) & 3, w = (p1 >> 14) & 15;
    int n = q * 256 + w * 16 + (lane & 15);
    int k = kt * 32 + (lane >> 4) * 8 + j;
    ((f16*)(ws + OFF_WIHF))[p1] = (f16)W_ih[n * 256 + k];
    return;
  }
  int p2 = p1 - 262144;
  if (p2 < 65536) {  // Wa1n f16 frags
    int j = p2 & 7, lane = (p2 >> 3) & 63, kt = (p2 >> 9) & 7, w = (p2 >> 12) & 15;
    int n = w * 16 + (lane & 15);
    int k = kt * 32 + (lane >> 4) * 8 + j;
    ((f16*)(ws + OFF_WA1NF))[p2] = (f16)Wa1[n * 512 + 256 + k];
    return;
  }
  int i2 = p2 - 65536;
  if (i2 < 65536) {  // actor/critic transposes
    int k = i2 >> 8, j = i2 & 255;
    ws[OFF_WA1HT + i2] = Wa1[j * 512 + k];
    ws[OFF_WC1T + i2] = Wc1[j * 256 + k];
  }
}

// Fused P_emb + A_emb via f16 MFMA. 16 vertices/block, 640 blocks, 1024 thr.
// (was 32 rows x 313 blocks: 1.22 blocks/CU -> 2nd dispatch round ran 57
// blocks at 22% utilization; 640 blocks = 2.5/CU smooths the tail)
__global__ __launch_bounds__(1024) void k_pemb(
    const float* __restrict__ ge, const float* __restrict__ b_ih,
    const float* __restrict__ b_hh, float* __restrict__ ws) {
  __shared__ f16 Alds[16 * 264];
  const int tid = threadIdx.x, w = tid >> 6, lane = tid & 63;
  const int l15 = lane & 15, quad = lane >> 4;
  const int vbase = blockIdx.x * 16;
  for (int i = tid; i < 16 * 256; i += 1024) {
    int row = i >> 8, col = i & 255;
    int v = min(vbase + row, NV - 1);
    Alds[row * 264 + col] = (f16)ge[(size_t)v * 256 + col];
  }
  __syncthreads();
  const f16* __restrict__ WIHF = (const f16*)(ws + OFF_WIHF);
  const f16* __restrict__ WANF = (const f16*)(ws + OFF_WA1NF);
  f32x4 Cp[4], Ca;
  Ca = (f32x4){0.f, 0.f, 0.f, 0.f};
#pragma unroll
  for (int q = 0; q < 4; ++q) Cp[q] = (f32x4){0.f, 0.f, 0.f, 0.f};
#pragma unroll
  for (int kt = 0; kt < 8; ++kt) {
    f16x8 a0 = *(const f16x8*)(Alds + l15 * 264 + kt * 32 + quad * 8);
#pragma unroll
    for (int q = 0; q < 4; ++q) {
      f16x8 bq = *(const f16x8*)(WIHF + (size_t)(((w * 4 + q) * 8 + kt) * 512 + lane * 8));
      Cp[q] = __builtin_amdgcn_mfma_f32_16x16x32_f16(a0, bq, Cp[q], 0, 0, 0);
    }
    f16x8 bn = *(const f16x8*)(WANF + (size_t)((w * 8 + kt) * 512 + lane * 8));
    Ca = __builtin_amdgcn_mfma_f32_16x16x32_f16(a0, bn, Ca, 0, 0, 0);
  }
  const int hc = w * 16 + l15;
  float bias[4];
#pragma unroll
  for (int q = 0; q < 4; ++q) {
    int n = q * 256 + hc;
    bias[q] = b_ih[n] + b_hh[n];
  }
  float* __restrict__ P = ws + OFF_PEMB;
  f16* __restrict__ A = (f16*)(ws + OFF_AEMB);
#pragma unroll
  for (int reg = 0; reg < 4; ++reg) {
    int v = vbase + quad * 4 + reg;
    if (v < NV) {
      f32x4 pw;
#pragma unroll
      for (int q = 0; q < 4; ++q) pw[q] = 128.f * (Cp[q][reg] + bias[q]);
      *(f32x4*)(P + (size_t)v * 1024 + hc * 4) = pw;
      A[(size_t)v * 256 + hc] = (f16)Ca[reg];
    }
  }
}

// LSTM + fused heads: 256 blocks x 1024 threads (16 waves), 2 paths/block.
// hA: 4 PHYSICAL rows {p0hi, p0lo, p1hi, p1lo}, stride 272 B; lane reads
// phys ((l15>>3)<<1)|(l15&1). Writes: quads 0,2 only. Path vertex ids staged
// in LDS. (R4 structure = best measured; R5's 8-wave variant lost wave-level
// MFMA/VALU overlap and regressed.)
__global__ __launch_bounds__(1024) void k_lstm(
    const int* __restrict__ paths, const int* __restrict__ path_lens,
    const int* __restrict__ neighbors, const int* __restrict__ n_nb,
    const float* __restrict__ ba1, const float* __restrict__ Wa2,
    const float* __restrict__ ba2, const float* __restrict__ bc1,
    const float* __restrict__ Wc2, const float* __restrict__ bc2,
    float* __restrict__ out, float* __restrict__ ws) {
  const int tid = threadIdx.x, w = tid >> 6, lane = tid & 63;
  const int l15 = lane & 15, quad = lane >> 4;
  const int g2 = blockIdx.x * 2;

  __shared__ char hA[2][4 * 272];    // [parity][phys*272 + k] fp8
  __shared__ int vtx[2][256];        // staged path vertex ids
  __shared__ float hfin[2][257];
  __shared__ float u_s[2][264];      // padded: index j + (j>>5)
  __shared__ float vred[2][256];
  __shared__ float part8[2][64][9];  // padded stride 9 (was 8: 16-way conflict)

  for (int i = tid; i < 2 * 4 * 272 / 4; i += 1024) ((int*)hA)[i] = 0;
  if (tid < 512) vtx[tid >> 8][tid & 255] = paths[(g2 + (tid >> 8)) * L + (tid & 255)];

  const int len0 = path_lens[g2], len1 = path_lens[g2 + 1];
  const int lmax = max(len0, len1);

  // persistent B-frags for mfma_scale 16x16x128 (64 VGPR)
  const v8i* __restrict__ WBv = (const v8i*)(ws + OFF_WB);
  v8i Bf[4][2];
#pragma unroll
  for (int q = 0; q < 4; ++q)
#pragma unroll
    for (int kt = 0; kt < 2; ++kt)
      Bf[q][kt] = WBv[(size_t)(((w * 4 + q) * 2 + kt) * 64 + lane)];

  const char* __restrict__ Pb = (const char*)(ws + OFF_PEMB);
  const int hc = w * 16 + l15;
  const int path = quad >> 1;            // 0,0,1,1 per quad
  const int lenv = path ? len1 : len0;
  const unsigned loff = (unsigned)hc * 16u;
  const int physr = ((l15 >> 3) << 1) | (l15 & 1);  // A-read phys row

  float cst = 0.f, hst = 0.f;
  f32x4 Cf[4];
#pragma unroll
  for (int q = 0; q < 4; ++q) Cf[q] = (f32x4){0.f, 0.f, 0.f, 0.f};
  __syncthreads();

  // P prefetch: pv = P row for step t; vn = vertex id for step t+1 (from LDS)
  f32x4 pv = *(const f32x4*)(Pb + (unsigned)vtx[path][0] * 4096u + loff);
  int vn = vtx[path][1];

  for (int t = 0; t < lmax; ++t) {
    // a-frags first (broadcast reads, hide LDS latency under the VALU below)
    const char* hp = hA[t & 1];
    const v8i a0 = *(const v8i*)(hp + physr * 272 + quad * 32);
    const v8i a1 = *(const v8i*)(hp + physr * 272 + 128 + quad * 32);
    // vertex id for t+2 (ds_read, consumed next iter)
    const int vn2 = vtx[path][min(t + 2, L - 1)];

    // C init: row 0 carries P, row 1 zero; rows [2],[3] accumulate garbage
    // (duplicated A rows land there; bounded, never read)
#pragma unroll
    for (int q = 0; q < 4; ++q) { Cf[q][0] = pv[q]; Cf[q][1] = 0.f; }

    // next-step P prefetch (stays in flight across the raw barrier)
    const f32x4 pvn = *(const f32x4*)(Pb + (unsigned)vn * 4096u + loff);

    __builtin_amdgcn_s_setprio(1);
#pragma unroll
    for (int q = 0; q < 4; ++q) Cf[q] = MFMA_SC(a0, Bf[q][0], Cf[q]);
#pragma unroll
    for (int q = 0; q < 4; ++q) Cf[q] = MFMA_SC(a1, Bf[q][1], Cf[q]);
    __builtin_amdgcn_s_setprio(0);

    // in-lane hi+lo combine
    float G[4];
#pragma unroll
    for (int q = 0; q < 4; ++q) G[q] = Cf[q][0] + Cf[q][1];

    const float inv = 1.f / 128.f;
    const float si = __builtin_amdgcn_rcpf(1.f + __expf(-G[0] * inv));
    const float sf = __builtin_amdgcn_rcpf(1.f + __expf(-G[1] * inv));
    const float tg = 1.f - 2.f * __builtin_amdgcn_rcpf(__expf(2.f * G[2] * inv) + 1.f);
    const float so = __builtin_amdgcn_rcpf(1.f + __expf(-G[3] * inv));
    const float cn = sf * cst + si * tg;
    const float hn = so * (1.f - 2.f * __builtin_amdgcn_rcpf(__expf(2.f * cn) + 1.f));
    if (t < lenv) { cst = cn; hst = hn; }

    if (!(quad & 1)) {  // quad0 -> phys 0,1 (path0); quad2 -> phys 2,3 (path1)
      char* nh = hA[(t + 1) & 1];
      const int hi = fp8_byte(16.f * hst);
      const float d = __builtin_amdgcn_cvt_f32_fp8(hi, 0);
      const int lo = fp8_byte(16.f * hst - d);
      nh[(path * 2 + 0) * 272 + hc] = (char)hi;
      nh[(path * 2 + 1) * 272 + hc] = (char)lo;
    }
    pv = pvn;
    vn = vn2;
    // raw barrier: fence LDS only, leave the global P prefetch in flight
    __builtin_amdgcn_sched_barrier(0);
    asm volatile("s_waitcnt lgkmcnt(0)" ::: "memory");
    __builtin_amdgcn_s_barrier();
    __builtin_amdgcn_sched_barrier(0);
  }

  // ---- fused heads for this block's 2 paths ----
  if (!(quad & 1)) hfin[path][hc] = hst;
  __syncthreads();

  const float* __restrict__ Wa1hT = ws + OFF_WA1HT;
  const float* __restrict__ Wc1T = ws + OFF_WC1T;
  const int p = tid >> 9;          // 0..1
  const int jj = tid & 255;
  const int dup = (tid >> 8) & 1;  // 0: actor-hidden, 1: critic-hidden
  if (dup == 0) {
    float aa = ba1[jj];
    for (int k = 0; k < 256; ++k) aa += Wa1hT[k * 256 + jj] * hfin[p][k];
    u_s[p][jj + (jj >> 5)] = aa;
  } else {
    float cc = bc1[jj];
    for (int k = 0; k < 256; ++k) cc += Wc1T[k * 256 + jj] * hfin[p][k];
    cc = cc > 0.f ? cc : __expf(cc) - 1.f;
    vred[p][jj] = cc * Wc2[jj];
  }
  __syncthreads();
  if (tid < 128) {
    const int pp = tid >> 6, lp = tid & 63;
    float s = vred[pp][lp] + vred[pp][lp + 64] + vred[pp][lp + 128] + vred[pp][lp + 192];
#pragma unroll
    for (int d = 32; d > 0; d >>= 1) s += __shfl_xor(s, d, 64);
    if (lp == 0) out[B * E + g2 + pp] = s + bc2[0];
  }
  // actor logits: (pa, e, jh) -> 32-long j-chunk
  const f16* __restrict__ A = (const f16*)(ws + OFF_AEMB);
  const int pa = tid >> 9, e = (tid >> 3) & 63, jh = tid & 7;
  const int nbv = neighbors[(g2 + pa) * 64 + e];
  float s = 0.f;
  const f16x8* __restrict__ Arow = (const f16x8*)(A + (size_t)nbv * 256 + jh * 32);
#pragma unroll
  for (int jo = 0; jo < 4; ++jo) {
    const f16x8 av = Arow[jo];
#pragma unroll
    for (int u = 0; u < 8; ++u) {
      const int j = jh * 32 + jo * 8 + u;
      float a = u_s[pa][j + (j >> 5)] + (float)av[u];
      a = a > 0.f ? a : __expf(a) - 1.f;
      s += a * Wa2[j];
    }
  }
  part8[pa][e][jh] = s;
  __syncthreads();
  if (tid < 128) {
    const int pp = tid >> 6, ee = tid & 63;
    const int ne = n_nb[g2 + pp];
    const bool valid = ee < ne;
    float le = -1e30f;
    if (valid) {
      le = ba2[0];
#pragma unroll
      for (int r = 0; r < 8; ++r) le += part8[pp][ee][r];
    }
    float m = le;
#pragma unroll
    for (int d = 32; d > 0; d >>= 1) m = fmaxf(m, __shfl_xor(m, d, 64));
    float pe = valid ? __expf(le - m) : 0.f;
    float sm = pe;
#pragma unroll
    for (int d = 32; d > 0; d >>= 1) sm += __shfl_xor(sm, d, 64);
    out[(g2 + pp) * 64 + ee] = pe / sm;
  }
}

extern "C" void kernel_launch(void* const* d_in, const int* in_sizes, int n_in,
                              void* d_out, int out_size, void* d_ws, size_t ws_size,
                              hipStream_t stream) {
  (void)in_sizes; (void)n_in; (void)out_size; (void)ws_size;
  const float* graph_emb = (const float*)d_in[0];
  const int* paths       = (const int*)d_in[1];
  const int* path_lens   = (const int*)d_in[2];
  const int* neighbors   = (const int*)d_in[3];
  const int* n_nb        = (const int*)d_in[4];
  const float* W_ih = (const float*)d_in[5];
  const float* W_hh = (const float*)d_in[6];
  const float* b_ih = (const float*)d_in[7];
  const float* b_hh = (const float*)d_in[8];
  const float* Wa1  = (const float*)d_in[9];
  const float* ba1  = (const float*)d_in[10];
  const float* Wa2  = (const float*)d_in[11];
  const float* ba2  = (const float*)d_in[12];
  const float* Wc1  = (const float*)d_in[13];
  const float* bc1  = (const float*)d_in[14];
  const float* Wc2  = (const float*)d_in[15];
  const float* bc2  = (const float*)d_in[16];
  float* out = (float*)d_out;
  float* ws = (float*)d_ws;

  hipLaunchKernelGGL(k_prep, dim3(1792), dim3(256), 0, stream, W_ih, W_hh, Wa1, Wc1, ws);
  hipLaunchKernelGGL(k_pemb, dim3(640), dim3(1024), 0, stream, graph_emb, b_ih, b_hh, ws);
  hipLaunchKernelGGL(k_lstm, dim3(256), dim3(1024), 0, stream, paths, path_lens,
                     neighbors, n_nb, ba1, Wa2, ba2, bc1, Wc2, bc2, out, ws);
}

// Round 7
// 354.274 us; speedup vs baseline: 1.0548x; 1.0334x over previous
//
#include <hip/hip_runtime.h>
#include <math.h>

#define NV 10000
#define B 512
#define L 256
#define E 64

typedef _Float16 f16;
typedef _Float16 f16x8 __attribute__((ext_vector_type(8)));
typedef float f32x4 __attribute__((ext_vector_type(4)));
typedef int v8i __attribute__((ext_vector_type(8)));

// ws layout (f32 offsets)
#define OFF_WA1HT 0u         // [256][256] f32  Wa1hT[k*256+j] = Wa1[j*512+k]
#define OFF_WC1T  65536u     // [256][256] f32
#define OFF_WB    131072u    // 262144 B: fp8 frags of 8*W_hh for mfma_scale 16x16x128
#define OFF_WIHF  196608u    // 262144 f16: frags of W_ih (16x16x32 f16 layout)
#define OFF_WA1NF 327680u    // 65536 f16: frags of Wa1n
#define OFF_PEMB  360448u    // 10,240,000 f32: P_perm[v][hc*4+q] = 128*(ge@W_ih^T+b)[v][q*256+hc]
#define OFF_AEMB  10600448u  // 2,560,000 f16: A_emb[v][256]
// total 11,880,448 f32 = 47.5 MB

__device__ __forceinline__ int fp8_byte(float x) {
  return __builtin_amdgcn_cvt_pk_fp8_f32(x, x, 0, false) & 0xFF;
}

#define MFMA_SC(a, b, c) \
  __builtin_amdgcn_mfma_scale_f32_16x16x128_f8f6f4((a), (b), (c), 0, 0, 0, 127, 0, 127)

__global__ __launch_bounds__(256) void k_prep(
    const float* __restrict__ W_ih, const float* __restrict__ W_hh,
    const float* __restrict__ Wa1, const float* __restrict__ Wc1,
    float* __restrict__ ws) {
  int idx = blockIdx.x * 256 + threadIdx.x;
  if (idx < 65536) {  // W_hh fp8 frags (x8) for 16x16x128: dword idx
    int d = idx & 7, lane = (idx >> 3) & 63, kt = (idx >> 9) & 1;
    int q = (idx >> 10) & 3, w = (idx >> 12) & 15;
    int l15 = lane & 15, quad = lane >> 4;
    int n = q * 256 + w * 16 + l15;
    int kb = kt * 128 + quad * 32 + d * 4;
    unsigned int word = 0;
#pragma unroll
    for (int jb = 0; jb < 4; ++jb)
      word |= ((unsigned int)fp8_byte(W_hh[n * 256 + kb + jb] * 8.f)) << (8 * jb);
    ((unsigned int*)(ws + OFF_WB))[idx] = word;
    return;
  }
  int p1 = idx - 65536;
  if (p1 < 262144) {  // W_ih f16 frags (16x16x32 layout, for k_pemb)
    int j = p1 & 7, lane = (p1 >> 3) & 63, kt = (p1 >> 9) & 7;
    int q = (p1 >> 12) & 3, w = (p1 >> 14) & 15;
    int n = q * 256 + w * 16 + (lane & 15);
    int k = kt * 32 + (lane >> 4) * 8 + j;
    ((f16*)(ws + OFF_WIHF))[p1] = (f16)W_ih[n * 256 + k];
    return;
  }
  int p2 = p1 - 262144;
  if (p2 < 65536) {  // Wa1n f16 frags
    int j = p2 & 7, lane = (p2 >> 3) & 63, kt = (p2 >> 9) & 7, w = (p2 >> 12) & 15;
    int n = w * 16 + (lane & 15);
    int k = kt * 32 + (lane >> 4) * 8 + j;
    ((f16*)(ws + OFF_WA1NF))[p2] = (f16)Wa1[n * 512 + 256 + k];
    return;
  }
  int i2 = p2 - 65536;
  if (i2 < 65536) {  // actor/critic transposes
    int k = i2 >> 8, j = i2 & 255;
    ws[OFF_WA1HT + i2] = Wa1[j * 512 + k];
    ws[OFF_WC1T + i2] = Wc1[j * 256 + k];
  }
}

// Fused P_emb + A_emb via f16 MFMA. 32 vertices/block, 313 blocks, 1024 thr.
// (640x16 variant regressed: k_pemb is L2-BW-bound on the 512KB weight frags;
// doubling blocks doubled weight re-reads)
__global__ __launch_bounds__(1024) void k_pemb(
    const float* __restrict__ ge, const float* __restrict__ b_ih,
    const float* __restrict__ b_hh, float* __restrict__ ws) {
  __shared__ f16 Alds[32 * 264];
  const int tid = threadIdx.x, w = tid >> 6, lane = tid & 63;
  const int l15 = lane & 15, quad = lane >> 4;
  const int vbase = blockIdx.x * 32;
  for (int i = tid; i < 32 * 256; i += 1024) {
    int row = i >> 8, col = i & 255;
    int v = min(vbase + row, NV - 1);
    Alds[row * 264 + col] = (f16)ge[(size_t)v * 256 + col];
  }
  __syncthreads();
  const f16* __restrict__ WIHF = (const f16*)(ws + OFF_WIHF);
  const f16* __restrict__ WANF = (const f16*)(ws + OFF_WA1NF);
  f32x4 Cp[2][4], Ca[2];
#pragma unroll
  for (int t = 0; t < 2; ++t) {
    Ca[t] = (f32x4){0.f, 0.f, 0.f, 0.f};
#pragma unroll
    for (int q = 0; q < 4; ++q) Cp[t][q] = (f32x4){0.f, 0.f, 0.f, 0.f};
  }
#pragma unroll
  for (int kt = 0; kt < 8; ++kt) {
    f16x8 a0 = *(const f16x8*)(Alds + l15 * 264 + kt * 32 + quad * 8);
    f16x8 a1 = *(const f16x8*)(Alds + (l15 + 16) * 264 + kt * 32 + quad * 8);
#pragma unroll
    for (int q = 0; q < 4; ++q) {
      f16x8 bq = *(const f16x8*)(WIHF + (size_t)(((w * 4 + q) * 8 + kt) * 512 + lane * 8));
      Cp[0][q] = __builtin_amdgcn_mfma_f32_16x16x32_f16(a0, bq, Cp[0][q], 0, 0, 0);
      Cp[1][q] = __builtin_amdgcn_mfma_f32_16x16x32_f16(a1, bq, Cp[1][q], 0, 0, 0);
    }
    f16x8 bn = *(const f16x8*)(WANF + (size_t)((w * 8 + kt) * 512 + lane * 8));
    Ca[0] = __builtin_amdgcn_mfma_f32_16x16x32_f16(a0, bn, Ca[0], 0, 0, 0);
    Ca[1] = __builtin_amdgcn_mfma_f32_16x16x32_f16(a1, bn, Ca[1], 0, 0, 0);
  }
  const int hc = w * 16 + l15;
  float bias[4];
#pragma unroll
  for (int q = 0; q < 4; ++q) {
    int n = q * 256 + hc;
    bias[q] = b_ih[n] + b_hh[n];
  }
  float* __restrict__ P = ws + OFF_PEMB;
  f16* __restrict__ A = (f16*)(ws + OFF_AEMB);
#pragma unroll
  for (int tile = 0; tile < 2; ++tile)
#pragma unroll
    for (int reg = 0; reg < 4; ++reg) {
      int v = vbase + tile * 16 + quad * 4 + reg;
      if (v < NV) {
        f32x4 pw;
#pragma unroll
        for (int q = 0; q < 4; ++q) pw[q] = 128.f * (Cp[tile][q][reg] + bias[q]);
        *(f32x4*)(P + (size_t)v * 1024 + hc * 4) = pw;
        A[(size_t)v * 256 + hc] = (f16)Ca[tile][reg];
      }
    }
}

// LSTM + fused heads: 256 blocks x 1024 threads (16 waves), 2 paths/block.
// Per-gate interleave: each gate q needs only ITS two MFMAs, so the body is
// four (2xMFMA -> gate-q VALU) chunks; a wave's q0 sigmoid overlaps its
// q1..q3 MFMAs in the pipe, and across 4 waves/SIMD the MFMA pipe and the
// VALU issue port saturate concurrently instead of phase-alternating.
__global__ __launch_bounds__(1024) void k_lstm(
    const int* __restrict__ paths, const int* __restrict__ path_lens,
    const int* __restrict__ neighbors, const int* __restrict__ n_nb,
    const float* __restrict__ ba1, const float* __restrict__ Wa2,
    const float* __restrict__ ba2, const float* __restrict__ bc1,
    const float* __restrict__ Wc2, const float* __restrict__ bc2,
    float* __restrict__ out, float* __restrict__ ws) {
  const int tid = threadIdx.x, w = tid >> 6, lane = tid & 63;
  const int l15 = lane & 15, quad = lane >> 4;
  const int g2 = blockIdx.x * 2;

  __shared__ char hA[2][4 * 272];    // [parity][phys*272 + k] fp8
  __shared__ int vtx[2][260];        // staged path vertex ids, clamp-extended
  __shared__ float hfin[2][257];
  __shared__ float u_s[2][264];      // padded: index j + (j>>5)
  __shared__ float vred[2][256];
  __shared__ float part8[2][64][9];  // padded stride 9

  for (int i = tid; i < 2 * 4 * 272 / 4; i += 1024) ((int*)hA)[i] = 0;
  for (int i = tid; i < 2 * 260; i += 1024) {
    const int p = i >= 260, tt = i - p * 260;
    vtx[p][tt] = paths[(g2 + p) * L + min(tt, L - 1)];
  }

  const int len0 = path_lens[g2], len1 = path_lens[g2 + 1];
  const int lmax = max(len0, len1);

  // persistent B-frags for mfma_scale 16x16x128 (64 VGPR)
  const v8i* __restrict__ WBv = (const v8i*)(ws + OFF_WB);
  v8i Bf[4][2];
#pragma unroll
  for (int q = 0; q < 4; ++q)
#pragma unroll
    for (int kt = 0; kt < 2; ++kt)
      Bf[q][kt] = WBv[(size_t)(((w * 4 + q) * 2 + kt) * 64 + lane)];

  const char* __restrict__ Pb = (const char*)(ws + OFF_PEMB);
  const int hc = w * 16 + l15;
  const int path = quad >> 1;            // 0,0,1,1 per quad
  const int lenv = path ? len1 : len0;
  const unsigned loff = (unsigned)hc * 16u;
  const int physr = ((l15 >> 3) << 1) | (l15 & 1);  // A-read phys row

  float cst = 0.f, hst = 0.f;
  f32x4 Cf[4];
#pragma unroll
  for (int q = 0; q < 4; ++q) Cf[q] = (f32x4){0.f, 0.f, 0.f, 0.f};
  __syncthreads();

  // P prefetch: pv = P row for step t; vn = vertex id for step t+1 (from LDS)
  f32x4 pv = *(const f32x4*)(Pb + (unsigned)vtx[path][0] * 4096u + loff);
  int vn = vtx[path][1];

  const float inv = 1.f / 128.f;
  for (int t = 0; t < lmax; ++t) {
    // a-frags first
    const char* hp = hA[t & 1];
    const v8i a0 = *(const v8i*)(hp + physr * 272 + quad * 32);
    const v8i a1 = *(const v8i*)(hp + physr * 272 + 128 + quad * 32);
    const int vn2 = vtx[path][t + 2];

    // next-step P prefetch (stays in flight across the raw barrier)
    const f32x4 pvn = *(const f32x4*)(Pb + (unsigned)vn * 4096u + loff);

    // ---- q0: input gate ----
    Cf[0][0] = pv[0]; Cf[0][1] = 0.f;
    Cf[0] = MFMA_SC(a0, Bf[0][0], Cf[0]);
    Cf[0] = MFMA_SC(a1, Bf[0][1], Cf[0]);
    const float si = __builtin_amdgcn_rcpf(1.f + __expf(-(Cf[0][0] + Cf[0][1]) * inv));

    // ---- q1: forget gate ----
    Cf[1][0] = pv[1]; Cf[1][1] = 0.f;
    Cf[1] = MFMA_SC(a0, Bf[1][0], Cf[1]);
    Cf[1] = MFMA_SC(a1, Bf[1][1], Cf[1]);
    const float sf = __builtin_amdgcn_rcpf(1.f + __expf(-(Cf[1][0] + Cf[1][1]) * inv));

    // ---- q2: cell candidate (tanh) ----
    Cf[2][0] = pv[2]; Cf[2][1] = 0.f;
    Cf[2] = MFMA_SC(a0, Bf[2][0], Cf[2]);
    Cf[2] = MFMA_SC(a1, Bf[2][1], Cf[2]);
    const float tg = 1.f - 2.f * __builtin_amdgcn_rcpf(
        __expf(2.f * (Cf[2][0] + Cf[2][1]) * inv) + 1.f);

    // ---- q3: output gate ----
    Cf[3][0] = pv[3]; Cf[3][1] = 0.f;
    Cf[3] = MFMA_SC(a0, Bf[3][0], Cf[3]);
    Cf[3] = MFMA_SC(a1, Bf[3][1], Cf[3]);
    const float so = __builtin_amdgcn_rcpf(1.f + __expf(-(Cf[3][0] + Cf[3][1]) * inv));

    const float cn = sf * cst + si * tg;
    const float hn = so * (1.f - 2.f * __builtin_amdgcn_rcpf(__expf(2.f * cn) + 1.f));
    if (t < lenv) { cst = cn; hst = hn; }

    if (!(quad & 1)) {  // quad0 -> phys 0,1 (path0); quad2 -> phys 2,3 (path1)
      char* nh = hA[(t + 1) & 1];
      const int hi = fp8_byte(16.f * hst);
      const float d = __builtin_amdgcn_cvt_f32_fp8(hi, 0);
      const int lo = fp8_byte(16.f * hst - d);
      nh[(path * 2 + 0) * 272 + hc] = (char)hi;
      nh[(path * 2 + 1) * 272 + hc] = (char)lo;
    }
    pv = pvn;
    vn = vn2;
    // raw barrier: fence LDS only, leave the global P prefetch in flight
    __builtin_amdgcn_sched_barrier(0);
    asm volatile("s_waitcnt lgkmcnt(0)" ::: "memory");
    __builtin_amdgcn_s_barrier();
    __builtin_amdgcn_sched_barrier(0);
  }

  // ---- fused heads for this block's 2 paths ----
  if (!(quad & 1)) hfin[path][hc] = hst;
  __syncthreads();

  const float* __restrict__ Wa1hT = ws + OFF_WA1HT;
  const float* __restrict__ Wc1T = ws + OFF_WC1T;
  const int p = tid >> 9;          // 0..1
  const int jj = tid & 255;
  const int dup = (tid >> 8) & 1;  // 0: actor-hidden, 1: critic-hidden
  if (dup == 0) {
    float aa = ba1[jj];
    for (int k = 0; k < 256; ++k) aa += Wa1hT[k * 256 + jj] * hfin[p][k];
    u_s[p][jj + (jj >> 5)] = aa;
  } else {
    float cc = bc1[jj];
    for (int k = 0; k < 256; ++k) cc += Wc1T[k * 256 + jj] * hfin[p][k];
    cc = cc > 0.f ? cc : __expf(cc) - 1.f;
    vred[p][jj] = cc * Wc2[jj];
  }
  __syncthreads();
  if (tid < 128) {
    const int pp = tid >> 6, lp = tid & 63;
    float s = vred[pp][lp] + vred[pp][lp + 64] + vred[pp][lp + 128] + vred[pp][lp + 192];
#pragma unroll
    for (int d = 32; d > 0; d >>= 1) s += __shfl_xor(s, d, 64);
    if (lp == 0) out[B * E + g2 + pp] = s + bc2[0];
  }
  // actor logits: (pa, e, jh) -> 32-long j-chunk
  const f16* __restrict__ A = (const f16*)(ws + OFF_AEMB);
  const int pa = tid >> 9, e = (tid >> 3) & 63, jh = tid & 7;
  const int nbv = neighbors[(g2 + pa) * 64 + e];
  float s = 0.f;
  const f16x8* __restrict__ Arow = (const f16x8*)(A + (size_t)nbv * 256 + jh * 32);
#pragma unroll
  for (int jo = 0; jo < 4; ++jo) {
    const f16x8 av = Arow[jo];
#pragma unroll
    for (int u = 0; u < 8; ++u) {
      const int j = jh * 32 + jo * 8 + u;
      float a = u_s[pa][j + (j >> 5)] + (float)av[u];
      a = a > 0.f ? a : __expf(a) - 1.f;
      s += a * Wa2[j];
    }
  }
  part8[pa][e][jh] = s;
  __syncthreads();
  if (tid < 128) {
    const int pp = tid >> 6, ee = tid & 63;
    const int ne = n_nb[g2 + pp];
    const bool valid = ee < ne;
    float le = -1e30f;
    if (valid) {
      le = ba2[0];
#pragma unroll
      for (int r = 0; r < 8; ++r) le += part8[pp][ee][r];
    }
    float m = le;
#pragma unroll
    for (int d = 32; d > 0; d >>= 1) m = fmaxf(m, __shfl_xor(m, d, 64));
    float pe = valid ? __expf(le - m) : 0.f;
    float sm = pe;
#pragma unroll
    for (int d = 32; d > 0; d >>= 1) sm += __shfl_xor(sm, d, 64);
    out[(g2 + pp) * 64 + ee] = pe / sm;
  }
}

extern "C" void kernel_launch(void* const* d_in, const int* in_sizes, int n_in,
                              void* d_out, int out_size, void* d_ws, size_t ws_size,
                              hipStream_t stream) {
  (void)in_sizes; (void)n_in; (void)out_size; (void)ws_size;
  const float* graph_emb = (const float*)d_in[0];
  const int* paths       = (const int*)d_in[1];
  const int* path_lens   = (const int*)d_in[2];
  const int* neighbors   = (const int*)d_in[3];
  const int* n_nb        = (const int*)d_in[4];
  const float* W_ih = (const float*)d_in[5];
  const float* W_hh = (const float*)d_in[6];
  const float* b_ih = (const float*)d_in[7];
  const float* b_hh = (const float*)d_in[8];
  const float* Wa1  = (const float*)d_in[9];
  const float* ba1  = (const float*)d_in[10];
  const float* Wa2  = (const float*)d_in[11];
  const float* ba2  = (const float*)d_in[12];
  const float* Wc1  = (const float*)d_in[13];
  const float* bc1  = (const float*)d_in[14];
  const float* Wc2  = (const float*)d_in[15];
  const float* bc2  = (const float*)d_in[16];
  float* out = (float*)d_out;
  float* ws = (float*)d_ws;

  hipLaunchKernelGGL(k_prep, dim3(1792), dim3(256), 0, stream, W_ih, W_hh, Wa1, Wc1, ws);
  hipLaunchKernelGGL(k_pemb, dim3(313), dim3(1024), 0, stream, graph_emb, b_ih, b_hh, ws);
  hipLaunchKernelGGL(k_lstm, dim3(256), dim3(1024), 0, stream, paths, path_lens,
                     neighbors, n_nb, ba1, Wa2, ba2, bc1, Wc2, bc2, out, ws);
}